// Round 6
// baseline (157.732 us; speedup 1.0000x reference)
//
#include <hip/hip_runtime.h>
#include <hip/hip_bf16.h>
#include <hip/hip_fp16.h>

// B=16, S=100, D=8192, P=100, W=3
constexpr int Dk   = 8192;
constexpr int Bb   = 16;
constexpr int Ss   = 100;
constexpr int Pp   = 100;
constexpr int MROW = 1632;     // 16 * 102 padded rows
constexpr int NT   = 20;       // n-tiles of 16 -> 320 cols (q|k|v|20 zero)
constexpr int NCC  = 320;
constexpr int NQ   = 304;      // qkv row stride (fp32)
constexpr int KG   = 1024;     // k-groups of 8 (K=8192)
constexpr int KC   = 32;       // K splits (chunk 256)
constexpr int CH   = 5;        // attn positions per block
constexpr int MB   = 26;       // m-blocks of 64 rows
constexpr int GFR  = MB * 4 * 20;              // frag-groups per slice = 2080

constexpr size_t B_SEG   = (size_t)NT * KG * 128;   // shorts per B segment
constexpr size_t PSTRIDE = (size_t)GFR * 256;       // halfs per part slice

typedef short s8v __attribute__((ext_vector_type(8)));
typedef short s4v __attribute__((ext_vector_type(4)));
typedef float f4v __attribute__((ext_vector_type(4)));

__device__ inline unsigned short f2bf_rne(float f) {
    unsigned u = __float_as_uint(f);
    u += 0x7fffu + ((u >> 16) & 1u);
    return (unsigned short)(u >> 16);
}

// Pack [wq|wk|wv|0] into hi/lo fragment layout [nt][kg][lane16][8].
__global__ __launch_bounds__(256) void pack_b(
    const float* __restrict__ wq, const float* __restrict__ wk,
    const float* __restrict__ wv,
    short* __restrict__ b_hi, short* __restrict__ b_lo) {
    const int id = blockIdx.x * 256 + threadIdx.x;
    const int n  = id % NCC;
    const int kg = id / NCC;
    if (kg >= KG) return;

    const float* w = nullptr; int p = 0;
    if (n < 100)      { w = wq; p = n; }
    else if (n < 200) { w = wk; p = n - 100; }
    else if (n < 300) { w = wv; p = n - 200; }

    s8v hi, lo;
    #pragma unroll
    for (int j = 0; j < 8; ++j) {
        const float v = w ? w[(size_t)(kg * 8 + j) * Pp + p] : 0.0f;
        const unsigned u = __float_as_uint(v);
        hi[j] = (short)(unsigned short)(u >> 16);                 // trunc split
        const float hf = __uint_as_float(u & 0xffff0000u);
        lo[j] = (short)f2bf_rne(v - hf);
    }
    const size_t doff = ((size_t)(n >> 4) * KG + kg) * 128 + (size_t)(n & 15) * 8;
    *(s8v*)(b_hi + doff) = hi;
    *(s8v*)(b_lo + doff) = lo;
}

// Fused QKV GEMM. Grid (26 mb, 32 kc); 256 thr = 4 waves, each 5 n-tiles.
// Block tile 64(M) x 320(N); wave tile 64x80 (4 m-frags x 5 n-frags).
// K-chunk 256 = 8 steps of 32. fp16 partials, lane-major packed layout.
__global__ __launch_bounds__(256) void qkv_fused(
    const float* __restrict__ x, const float* __restrict__ fpad,
    const float* __restrict__ bpad,
    const short* __restrict__ b_hi, const short* __restrict__ b_lo,
    unsigned short* __restrict__ part) {
    __shared__ __align__(16) short ahis[2048];   // [frag4][kg4][lane16][8]
    __shared__ __align__(16) short alos[2048];

    const int mb   = blockIdx.x;         // 0..25
    const int kc   = blockIdx.y;         // 0..31
    const int tid  = threadIdx.x;
    const int w    = tid >> 6;           // nw 0..3
    const int l    = tid & 63;
    const int m    = l & 15;
    const int quad = l >> 4;

    // staging role: thread -> (row srow, k-quad skq), 2 float4 per step
    const int srow = tid >> 2;           // 0..63
    const int skq  = tid & 3;            // 0..3
    const float* sp;
    {
        const int r = mb * 64 + srow;
        if (r >= MROW) sp = fpad;        // junk rows, never read downstream
        else {
            const int b = r / 102, rr = r - b * 102;
            if (rr == 0)        sp = fpad + (size_t)b * Dk;
            else if (rr == 101) sp = bpad + (size_t)b * Dk;
            else                sp = x + ((size_t)b * Ss + (rr - 1)) * Dk;
        }
        sp += kc * 256 + skq * 4;
    }
    // LDS write offsets for klocal = skq*4 and 16 + skq*4
    const int w0 = (((srow >> 4) * 4 + (skq >> 1)) * 16 + (srow & 15)) * 8 + (skq & 1) * 4;
    const int w1 = (((srow >> 4) * 4 + 2 + (skq >> 1)) * 16 + (srow & 15)) * 8 + (skq & 1) * 4;

    f4v acc[4][5];
    #pragma unroll
    for (int i = 0; i < 4; ++i)
        #pragma unroll
        for (int j = 0; j < 5; ++j) {
            f4v z = {0.f, 0.f, 0.f, 0.f};
            acc[i][j] = z;
        }

    #pragma unroll
    for (int s = 0; s < 8; ++s) {
        // ---- stage A: 64x32 fp32 -> hi/lo bf16 -> LDS fragment layout ----
        const float4 va = *(const float4*)(sp + s * 32);
        const float4 vb = *(const float4*)(sp + s * 32 + 16);
        const float vv[8] = {va.x, va.y, va.z, va.w, vb.x, vb.y, vb.z, vb.w};
        s4v h0, l0, h1, l1;
        #pragma unroll
        for (int jj = 0; jj < 4; ++jj) {
            unsigned u = __float_as_uint(vv[jj]);
            h0[jj] = (short)(unsigned short)(u >> 16);
            l0[jj] = (short)f2bf_rne(vv[jj] - __uint_as_float(u & 0xffff0000u));
            u = __float_as_uint(vv[4 + jj]);
            h1[jj] = (short)(unsigned short)(u >> 16);
            l1[jj] = (short)f2bf_rne(vv[4 + jj] - __uint_as_float(u & 0xffff0000u));
        }
        __syncthreads();                 // prev step's LDS reads complete
        *(s4v*)&ahis[w0] = h0;  *(s4v*)&alos[w0] = l0;
        *(s4v*)&ahis[w1] = h1;  *(s4v*)&alos[w1] = l1;
        __syncthreads();                 // staged data visible

        // ---- A fragments from LDS ----
        s8v ah[4], al[4];
        #pragma unroll
        for (int i = 0; i < 4; ++i) {
            ah[i] = *(const s8v*)&ahis[((i * 4 + quad) * 16 + m) * 8];
            al[i] = *(const s8v*)&alos[((i * 4 + quad) * 16 + m) * 8];
        }

        // ---- B from global (L2-resident packed), 60 MFMAs ----
        const int kgg = kc * 32 + s * 4 + quad;
        #pragma unroll
        for (int j = 0; j < 5; ++j) {
            const size_t bo = ((size_t)(w * 5 + j) * KG + kgg) * 128 + (size_t)m * 8;
            const s8v bh = *(const s8v*)(b_hi + bo);
            const s8v bl = *(const s8v*)(b_lo + bo);
            #pragma unroll
            for (int i = 0; i < 4; ++i)
                acc[i][j] = __builtin_amdgcn_mfma_f32_16x16x32_bf16(ah[i], bh, acc[i][j], 0, 0, 0);
            #pragma unroll
            for (int i = 0; i < 4; ++i)
                acc[i][j] = __builtin_amdgcn_mfma_f32_16x16x32_bf16(al[i], bh, acc[i][j], 0, 0, 0);
            #pragma unroll
            for (int i = 0; i < 4; ++i)
                acc[i][j] = __builtin_amdgcn_mfma_f32_16x16x32_bf16(ah[i], bl, acc[i][j], 0, 0, 0);
        }
    }

    // ---- store fp16 partials, lane-major: 512B contiguous per (i,j) ----
    #pragma unroll
    for (int i = 0; i < 4; ++i) {
        #pragma unroll
        for (int j = 0; j < 5; ++j) {
            const int g = (mb * 4 + w) * 20 + i * 5 + j;
            const size_t idx = (((size_t)kc * GFR + g) * 64 + l) * 4;
            ushort4 u;
            u.x = __half_as_ushort(__float2half(acc[i][j][0]));
            u.y = __half_as_ushort(__float2half(acc[i][j][1]));
            u.z = __half_as_ushort(__float2half(acc[i][j][2]));
            u.w = __half_as_ushort(__float2half(acc[i][j][3]));
            *(ushort4*)(part + idx) = u;
        }
    }
}

// Reduce KC fp16 partial slices -> fp32 qkv[row][col] (stride 304).
// grid 520 x 256: thread = (g, l); 32 ushort4 loads, 4 scattered f32 stores.
__global__ __launch_bounds__(256) void reduce_k(
    const unsigned short* __restrict__ part, float* __restrict__ qkv) {
    const int t = blockIdx.x * 256 + threadIdx.x;
    const int g = t >> 6, l = t & 63;
    const size_t base = ((size_t)g * 64 + l) * 4;

    float s0 = 0.f, s1 = 0.f, s2 = 0.f, s3 = 0.f;
    #pragma unroll
    for (int k = 0; k < KC; ++k) {
        const ushort4 u = *(const ushort4*)(part + base + (size_t)k * PSTRIDE);
        s0 += __half2float(__ushort_as_half(u.x));
        s1 += __half2float(__ushort_as_half(u.y));
        s2 += __half2float(__ushort_as_half(u.z));
        s3 += __half2float(__ushort_as_half(u.w));
    }

    const int mb = g / 80, rem = g - mb * 80;
    const int nw = rem / 20, fi = rem - nw * 20;
    const int i = fi / 5, j = fi - i * 5;
    const int quad = l >> 4, m = l & 15;
    const int row = mb * 64 + i * 16 + quad * 4;
    const int col = (nw * 5 + j) * 16 + m;
    if (col < NQ) {
        float* q = qkv + (size_t)row * NQ + col;
        q[0]      = s0;
        q[NQ]     = s1;
        q[2 * NQ] = s2;
        q[3 * NQ] = s3;
    }
}

// Attention on reduced fp32 qkv. Block = (b, chunk of 5 positions); grid 320.
__global__ __launch_bounds__(256) void attn3(
    const float* __restrict__ qkv, float* __restrict__ out) {
    const int blk = blockIdx.x;          // 0..319
    const int b  = blk / (Ss / CH);
    const int c  = blk % (Ss / CH);
    const int s0 = c * CH;
    const int tid = threadIdx.x;

    __shared__ float red[CH + 2][304];   // rows s0..s0+6, cols 0..299
    __shared__ float sc[CH][3];

    for (int idx = tid; idx < (CH + 2) * 300; idx += 256) {
        const int row = idx / 300, col = idx % 300;
        red[row][col] = qkv[(size_t)(b * 102 + s0 + row) * NQ + col];
    }
    __syncthreads();

    // 15 score dots, one per 16-lane group: (ss,u): Q[ss+1].K[ss+u]
    if (tid < CH * 3 * 16) {
        const int d = tid >> 4, g = tid & 15;
        const int ss = d / 3, u = d % 3;
        float ps = 0.0f;
        #pragma unroll
        for (int t = 0; t < 7; ++t) {
            const int p = g + t * 16;
            if (p < Pp) ps += red[ss + 1][p] * red[ss + u][100 + p];
        }
        #pragma unroll
        for (int off = 8; off > 0; off >>= 1) ps += __shfl_down(ps, off, 16);
        if (g == 0) sc[ss][u] = ps;
    }
    __syncthreads();

    for (int idx = tid; idx < CH * Pp; idx += 256) {
        const int ss = idx / Pp, p = idx % Pp;
        const float a0 = sc[ss][0], a1 = sc[ss][1], a2 = sc[ss][2];
        const float mx = fmaxf(a0, fmaxf(a1, a2));
        const float e0 = __expf(a0 - mx), e1 = __expf(a1 - mx), e2 = __expf(a2 - mx);
        const float inv = 1.0f / (e0 + e1 + e2);
        out[(size_t)(b * Ss + s0 + ss) * Pp + p] =
            inv * (e0 * red[ss][200 + p] + e1 * red[ss + 1][200 + p] +
                   e2 * red[ss + 2][200 + p]);
    }
}

extern "C" void kernel_launch(void* const* d_in, const int* in_sizes, int n_in,
                              void* d_out, int out_size, void* d_ws, size_t ws_size,
                              hipStream_t stream) {
    const float* x    = (const float*)d_in[0];
    const float* wq   = (const float*)d_in[1];
    const float* wk   = (const float*)d_in[2];
    const float* wv   = (const float*)d_in[3];
    const float* fpad = (const float*)d_in[4];
    const float* bpad = (const float*)d_in[5];
    float* out = (float*)d_out;

    short* b_hi = (short*)d_ws;                              // 5.24 MB
    short* b_lo = b_hi + B_SEG;                              // 5.24 MB
    unsigned short* part = (unsigned short*)(b_lo + B_SEG);  // 32*GFR*256 fp16 = 34.1 MB
    float* qkv = (float*)(part + (size_t)KC * PSTRIDE);      // 1664*304 fp32 = 2.0 MB
    // total ws ~46.6 MB; part/qkv fully overwritten, no zeroing needed

    pack_b<<<(NCC * KG) / 256, 256, 0, stream>>>(wq, wk, wv, b_hi, b_lo);
    qkv_fused<<<dim3(MB, KC), 256, 0, stream>>>(x, fpad, bpad, b_hi, b_lo, part);
    reduce_k<<<(GFR * 64) / 256, 256, 0, stream>>>(part, qkv);
    attn3<<<Bb * (Ss / CH), 256, 0, stream>>>(qkv, out);
}